// Round 1
// baseline (838.866 us; speedup 1.0000x reference)
//
#include <hip/hip_runtime.h>
#include <math.h>

#define N_USERS 100000
#define N_ITEMS 50000
#define N_EDGES 2000000
#define D       64
#define EPS     1e-12f

// ---------------------------------------------------------------------------
// Kernel 1: per-row inverse norm.  One 64-lane wave per row (D == 64).
// invn[r] = 1 / max(||x_r||, EPS)
// ---------------------------------------------------------------------------
__global__ void norm_kernel(const float* __restrict__ x,
                            float* __restrict__ invn,
                            int nrows) {
    int gid  = blockIdx.x * blockDim.x + threadIdx.x;
    int wave = gid >> 6;
    int lane = gid & 63;
    if (wave >= nrows) return;

    float v  = x[wave * D + lane];
    float ss = v * v;
    #pragma unroll
    for (int m = 32; m >= 1; m >>= 1) ss += __shfl_xor(ss, m);

    if (lane == 0) {
        invn[wave] = 1.0f / fmaxf(sqrtf(ss), EPS);
    }
}

// ---------------------------------------------------------------------------
// Kernel 2: per-edge compute + scatter.  One 64-lane wave per edge.
// lane = feature dim.  Gathers x_u, x_i once; dot product via shfl reduce;
// scalar weight; two atomic scatters.
// ---------------------------------------------------------------------------
__global__ void edge_kernel(const float* __restrict__ x,
                            const float* __restrict__ beta,
                            const float* __restrict__ du,
                            const float* __restrict__ di,
                            const int*   __restrict__ u,
                            const int*   __restrict__ i,
                            const float* __restrict__ invn,
                            float* __restrict__ out) {
    int gid  = blockIdx.x * blockDim.x + threadIdx.x;
    int wave = gid >> 6;
    int lane = gid & 63;
    if (wave >= N_EDGES) return;

    int uu = u[wave];                 // wave-uniform load (single transaction)
    int ii = i[wave];

    const float xu = x[uu * D + lane];
    const float xi = x[(N_USERS + ii) * D + lane];

    float p = xu * xi;
    #pragma unroll
    for (int m = 32; m >= 1; m >>= 1) p += __shfl_xor(p, m);

    // all lanes now hold the full dot product
    float s   = p * invn[uu] * invn[N_USERS + ii] - beta[uu];
    float sig = 1.0f / (1.0f + __expf(-s));
    float w   = 4.0f * sig * (1.0f - sig) * rsqrtf(du[uu]) * rsqrtf(di[ii]);

    atomicAdd(&out[uu * D + lane],             w * xi);
    atomicAdd(&out[(N_USERS + ii) * D + lane], w * xu);
}

// ---------------------------------------------------------------------------
extern "C" void kernel_launch(void* const* d_in, const int* in_sizes, int n_in,
                              void* d_out, int out_size, void* d_ws, size_t ws_size,
                              hipStream_t stream) {
    const float* x    = (const float*)d_in[0];
    const float* beta = (const float*)d_in[1];
    const float* du   = (const float*)d_in[2];
    const float* di   = (const float*)d_in[3];
    const int*   u    = (const int*)d_in[4];
    const int*   i    = (const int*)d_in[5];

    float* out  = (float*)d_out;
    float* invn = (float*)d_ws;       // 150000 floats = 600 KB

    const int nrows = N_USERS + N_ITEMS;

    // zero the output accumulator (harness poisons d_out; atomics need zeros)
    hipMemsetAsync(d_out, 0, (size_t)out_size * sizeof(float), stream);

    // inverse norms: one wave per row, 4 waves per block
    {
        int waves_per_block = 4;
        int block = waves_per_block * 64;
        int grid  = (nrows + waves_per_block - 1) / waves_per_block;
        norm_kernel<<<grid, block, 0, stream>>>(x, invn, nrows);
    }

    // per-edge: one wave per edge, 4 waves per block
    {
        int waves_per_block = 4;
        int block = waves_per_block * 64;
        int grid  = (N_EDGES + waves_per_block - 1) / waves_per_block;
        edge_kernel<<<grid, block, 0, stream>>>(x, beta, du, di, u, i, invn, out);
    }
}